// Round 7
// baseline (472.448 us; speedup 1.0000x reference)
//
#include <hip/hip_runtime.h>
#include <hip/hip_bf16.h>

typedef __attribute__((ext_vector_type(8))) short short8;
typedef __attribute__((ext_vector_type(4))) float f32x4;
typedef __attribute__((ext_vector_type(2))) float f32x2;

#define LOG2E  1.44269504088896340736f
#define NLOG2E (-1.44269504088896340736f)
#define TLOG2E (2.88539008177792681472f)

#define HES 168   // h_ext row stride in shorts: 84 dw == 20 mod 32 -> 2-way (free) on b128

__device__ __forceinline__ unsigned short f2bf(float f) {
  unsigned u = __builtin_bit_cast(unsigned, f);
  u += 0x7fffu + ((u >> 16) & 1u);
  return (unsigned short)(u >> 16);
}

// -------------------- small setup: P tables only --------------------------
__global__ __launch_bounds__(256) void ptab_kernel(
    const float* __restrict__ E_time, const float* __restrict__ E_week,
    const float* __restrict__ Wh_x, const float* __restrict__ bh,
    const float* __restrict__ Ww_x, const float* __restrict__ bw,
    float* __restrict__ Ptime, float* __restrict__ Pweek)
{
  const int b = blockIdx.x;
  for (int c = threadIdx.x; c < 384; c += 256) {
    if (b < 24) {
      float acc = bh[c];
      for (int d = 0; d < 128; ++d)
        acc = fmaf(E_time[b * 128 + d], Wh_x[d * 384 + c], acc);
      Ptime[b * 384 + c] = acc;
    } else {
      const int r = b - 24;
      float acc = bw[c];
      for (int d = 0; d < 128; ++d)
        acc = fmaf(E_week[r * 128 + d], Ww_x[d * 384 + c], acc);
      Pweek[r * 384 + c] = acc;
    }
  }
}

// -------------------- persistent GRU kernel v7 ----------------------------
// Blocks 0..95: TWO independent 16-row chains per block (chunks 2b, 2b+1),
// 512 threads = 8 waves; waves 0-3 = chain A, 4-7 = chain B, phase-shifted
// by half a step. Each half-step one chain does {ds_read + MFMA} while the
// other does {gates + h-write} -> LDS/MFMA/trans pipes overlap by construction.
// Blocks 96..295: MLP weight transpose tiles (uses the idle CUs).
__global__ __launch_bounds__(512, 2) void gru_kernel(
    const float* __restrict__ spatial,
    const int* __restrict__ hour_idx,
    const int* __restrict__ week_idx,
    const float* __restrict__ Ws_x,
    const float* __restrict__ Ws_h, const float* __restrict__ bs,
    const float* __restrict__ Wh_h, const float* __restrict__ bh,
    const float* __restrict__ Ww_h, const float* __restrict__ bw,
    const float* __restrict__ Ptime, const float* __restrict__ Pweek,
    const float* __restrict__ W1, const float* __restrict__ W2,
    const float* __restrict__ W3, const float* __restrict__ W4,
    unsigned short* __restrict__ Wt,
    float* __restrict__ fs, float* __restrict__ fh, float* __restrict__ fw)
{
  __shared__ __align__(16) unsigned short smem[4][16 * HES];  // 21.5 KB

  const int tid = threadIdx.x;

  // ================= transpose blocks (1 tile of 64x64 each) =============
  if (blockIdx.x >= 96) {
    float (*ttile)[65] = (float (*)[65])smem;   // 16.6 KB fits
    int tb = blockIdx.x - 96;                   // 0..199
    const float* src; unsigned short* dst; int K, N, tk, tn;
    if (tb < 32)       { src = W1; dst = Wt;          K = 128;  N = 1024; tk = tb >> 4; tn = tb & 15; }
    else if (tb < 160) { tb -= 32;  src = W2; dst = Wt + 131072; K = 1024; N = 512;  tk = tb >> 3; tn = tb & 7; }
    else if (tb < 192) { tb -= 160; src = W3; dst = Wt + 655360; K = 512;  N = 256;  tk = tb >> 2; tn = tb & 3; }
    else               { tb -= 192; src = W4; dst = Wt + 786432; K = 256;  N = 128;  tk = tb >> 1; tn = tb & 1; }
    const int tx = tid & 63, ty = tid >> 6;     // ty 0..7
    const int k0 = tk * 64, n0 = tn * 64;
    #pragma unroll
    for (int i = 0; i < 8; ++i)
      ttile[ty * 8 + i][tx] = src[(k0 + ty * 8 + i) * N + n0 + tx];
    __syncthreads();
    #pragma unroll
    for (int i = 0; i < 8; ++i)
      dst[(n0 + ty * 8 + i) * K + k0 + tx] = f2bf(ttile[tx][ty * 8 + i]);
    return;
  }

  // ================= GRU blocks =================
  const int lane = tid & 63;
  const int wv   = tid >> 6;       // 0..7
  const int ch   = wv >> 2;        // 0 = chain A, 1 = chain B
  const int wvc  = wv & 3;         // wave within chain
  const int ar   = lane & 15;
  const int akg  = lane >> 4;      // 0..3

  const int chunk = blockIdx.x * 2 + ch;   // 0..191
  const int gru   = chunk >> 6;
  const int row0  = (chunk & 63) * 16;

  const float* __restrict__ Wh   = (gru == 0) ? Ws_h : (gru == 1) ? Wh_h : Ww_h;
  const float* __restrict__ bvec = (gru == 0) ? bs   : (gru == 1) ? bh   : bw;
  float* __restrict__ fout       = (gru == 0) ? fs   : (gru == 1) ? fh   : fw;
  const float* __restrict__ Ptab = (gru == 1) ? Ptime : Pweek;
  const int* __restrict__ idxg   = (gru == 1) ? hour_idx : week_idx;
  const int NR = (gru == 1) ? 24 : 7;

  // two owned col-tiles per wave (16 cols each, halves of 0..127)
  const int jc[2] = {wvc * 16 + ar, 64 + wvc * 16 + ar};

  // ---- weight fragments: [jh][0..4]=z, [5..9]=r, [10..13]=nh, [14]=nx ----
  short8 wf[2][15];
  #pragma unroll
  for (int jh = 0; jh < 2; ++jh) {
    #pragma unroll
    for (int g = 0; g < 2; ++g) {
      #pragma unroll
      for (int ks = 0; ks < 5; ++ks) {
        short8 f;
        #pragma unroll
        for (int q = 0; q < 8; ++q) {
          const int k = ks * 32 + akg * 8 + q;
          const int col = g * 128 + jc[jh];
          float v;
          if (k < 128) v = Wh[k * 384 + col];
          else {
            const int p = k - 128;
            if (gru == 0) v = (p == 0) ? Ws_x[col] : (p == 1) ? Ws_x[384 + col] : 0.f;
            else          v = (p < NR) ? Ptab[p * 384 + col] : 0.f;
          }
          f[q] = (short)f2bf(v * NLOG2E);
        }
        wf[jh][g * 5 + ks] = f;
      }
    }
    #pragma unroll
    for (int ks = 0; ks < 4; ++ks) {   // nh (h-side, K=128)
      short8 f;
      #pragma unroll
      for (int q = 0; q < 8; ++q) {
        const int k = ks * 32 + akg * 8 + q;
        f[q] = (short)f2bf(Wh[k * 384 + 256 + jc[jh]] * TLOG2E);
      }
      wf[jh][10 + ks] = f;
    }
    {                                  // nx (extension rows only)
      short8 f;
      #pragma unroll
      for (int q = 0; q < 8; ++q) {
        const int p = akg * 8 + q;
        const int col = 256 + jc[jh];
        float v;
        if (gru == 0) v = (p == 0) ? Ws_x[col] : (p == 1) ? Ws_x[384 + col] : 0.f;
        else          v = (p < NR) ? Ptab[p * 384 + col] : 0.f;
        f[q] = (short)f2bf(v * TLOG2E);
      }
      wf[jh][14] = f;
    }
  }

  float bz[2], br[2], bnh[2], bnx[2];
  #pragma unroll
  for (int jh = 0; jh < 2; ++jh) {
    const int j = jc[jh];
    bz[jh]  = (bvec[384 + j]       + (gru == 0 ? bvec[j]       : 0.f)) * NLOG2E;
    br[jh]  = (bvec[384 + 128 + j] + (gru == 0 ? bvec[128 + j] : 0.f)) * NLOG2E;
    bnh[jh] = bvec[384 + 256 + j] * TLOG2E;
    bnx[jh] = (gru == 0 ? bvec[256 + j] : 0.f) * TLOG2E;
  }

  // my chain's double buffer
  unsigned short (*buf)[16 * HES] = &smem[ch * 2];

  // zero both buffers of my chain (256 threads per chain)
  for (int e = wvc * 64 + lane; e < 2 * 16 * HES; e += 256)
    ((unsigned short*)buf)[e] = 0;
  __syncthreads();

  // maintenance lanes: 16 per chain (ar==0), row = wvc*4+akg
  const bool mt   = (ar == 0);
  const int mrow  = wvc * 4 + akg;
  f32x2 spn = {0.f, 0.f};
  int ix_prev = 0, ix_cur = 0, ix_next = 0;
  if (mt) {
    if (gru == 0) {
      const f32x2 s0 = *(const f32x2*)&spatial[(row0 + mrow) * 512];
      unsigned pk;
      asm("v_cvt_pk_bf16_f32 %0, %1, %2" : "=v"(pk) : "v"(s0.x), "v"(s0.y));
      *(unsigned*)&buf[0][mrow * HES + 128] = pk;
      spn = *(const f32x2*)&spatial[(row0 + mrow) * 512 + 2];
    } else {
      ix_cur = idxg[(row0 + mrow) * 256];
      buf[0][mrow * HES + 128 + ix_cur] = 0x3F80;   // bf16 1.0
      ix_next = idxg[(row0 + mrow) * 256 + 1];
    }
  }
  __syncthreads();

  float hst[2][4];
  #pragma unroll
  for (int jh = 0; jh < 2; ++jh)
    #pragma unroll
    for (int q = 0; q < 4; ++q) hst[jh][q] = 0.f;

  f32x4 az[2], arr[2], anh[2], anx[2];
  const int abase = ar * HES;

  // ---- M phase: ds_read A-frags + 30 MFMA -> persistent accs ----
  auto MPH = [&](int t) {
    const unsigned short* __restrict__ hb = buf[t & 1];
    short8 a[5];
    #pragma unroll
    for (int ks = 0; ks < 5; ++ks)
      a[ks] = *(const short8*)&hb[abase + ks * 32 + akg * 8];
    #pragma unroll
    for (int jh = 0; jh < 2; ++jh) {
      az[jh]  = f32x4{bz[jh],  bz[jh],  bz[jh],  bz[jh]};
      arr[jh] = f32x4{br[jh],  br[jh],  br[jh],  br[jh]};
      anh[jh] = f32x4{bnh[jh], bnh[jh], bnh[jh], bnh[jh]};
      anx[jh] = f32x4{bnx[jh], bnx[jh], bnx[jh], bnx[jh]};
      #pragma unroll
      for (int ks = 0; ks < 4; ++ks) {
        az[jh]  = __builtin_amdgcn_mfma_f32_16x16x32_bf16(a[ks], wf[jh][ks],      az[jh],  0, 0, 0);
        arr[jh] = __builtin_amdgcn_mfma_f32_16x16x32_bf16(a[ks], wf[jh][5 + ks],  arr[jh], 0, 0, 0);
        anh[jh] = __builtin_amdgcn_mfma_f32_16x16x32_bf16(a[ks], wf[jh][10 + ks], anh[jh], 0, 0, 0);
      }
      az[jh]  = __builtin_amdgcn_mfma_f32_16x16x32_bf16(a[4], wf[jh][4],  az[jh],  0, 0, 0);
      arr[jh] = __builtin_amdgcn_mfma_f32_16x16x32_bf16(a[4], wf[jh][9],  arr[jh], 0, 0, 0);
      anx[jh] = __builtin_amdgcn_mfma_f32_16x16x32_bf16(a[4], wf[jh][14], anx[jh], 0, 0, 0);
    }
  };

  // ---- G phase: gates (merged rcp) + h-write + ext maintenance ----
  auto GPH = [&](int t) {
    unsigned short* __restrict__ ho = buf[(t + 1) & 1];
    #pragma unroll
    for (int jh = 0; jh < 2; ++jh) {
      float zg[4], rg[4], pz[4], pr[4];
      #pragma unroll
      for (int q = 0; q < 4; ++q) {
        pz[q] = 1.f + __builtin_amdgcn_exp2f(az[jh][q]);
        pr[q] = 1.f + __builtin_amdgcn_exp2f(arr[jh][q]);
      }
      #pragma unroll
      for (int p = 0; p < 4; p += 2) {
        const float A0 = pz[p] * pr[p];
        const float A1 = pz[p + 1] * pr[p + 1];
        const float inv = __builtin_amdgcn_rcpf(A0 * A1);
        const float t1 = A1 * inv, t0 = A0 * inv;
        zg[p]     = pr[p] * t1;     rg[p]     = pz[p] * t1;
        zg[p + 1] = pr[p + 1] * t0; rg[p + 1] = pz[p + 1] * t0;
      }
      float ph[4];
      #pragma unroll
      for (int q = 0; q < 4; ++q)
        ph[q] = 1.f + __builtin_amdgcn_exp2f(fmaf(rg[q], anh[jh][q], anx[jh][q]));
      float hn4[4];
      #pragma unroll
      for (int p = 0; p < 4; p += 2) {
        const float inv = __builtin_amdgcn_rcpf(ph[p] * ph[p + 1]);
        const float i0 = ph[p + 1] * inv;
        const float i1 = ph[p] * inv;
        const float hh0 = fmaf(-2.f, i0, 1.f);
        const float hh1 = fmaf(-2.f, i1, 1.f);
        hn4[p]     = fmaf(zg[p],     hst[jh][p]     - hh0, hh0);
        hn4[p + 1] = fmaf(zg[p + 1], hst[jh][p + 1] - hh1, hh1);
        hst[jh][p] = hn4[p]; hst[jh][p + 1] = hn4[p + 1];
      }
      unsigned p01, p23;
      asm("v_cvt_pk_bf16_f32 %0, %1, %2" : "=v"(p01) : "v"(hn4[0]), "v"(hn4[1]));
      asm("v_cvt_pk_bf16_f32 %0, %1, %2" : "=v"(p23) : "v"(hn4[2]), "v"(hn4[3]));
      const int j = jc[jh];
      ho[(akg * 4 + 0) * HES + j] = (unsigned short)(p01 & 0xffffu);
      ho[(akg * 4 + 1) * HES + j] = (unsigned short)(p01 >> 16);
      ho[(akg * 4 + 2) * HES + j] = (unsigned short)(p23 & 0xffffu);
      ho[(akg * 4 + 3) * HES + j] = (unsigned short)(p23 >> 16);
    }
    // extension values for t+1 (read by this chain's M(t+1) next half-step)
    if (mt && t + 1 < 256) {
      if (gru == 0) {
        unsigned pk;
        asm("v_cvt_pk_bf16_f32 %0, %1, %2" : "=v"(pk) : "v"(spn.x), "v"(spn.y));
        *(unsigned*)&ho[mrow * HES + 128] = pk;
        if (t + 2 < 256) spn = *(const f32x2*)&spatial[(row0 + mrow) * 512 + 2 * (t + 2)];
      } else {
        if (t >= 1) ho[mrow * HES + 128 + ix_prev] = 0;   // clear onehot(t-1)
        ho[mrow * HES + 128 + ix_next] = 0x3F80;          // set onehot(t+1)
        ix_prev = ix_cur; ix_cur = ix_next;
        if (t + 2 < 256) ix_next = idxg[(row0 + mrow) * 256 + t + 2];
      }
    }
  };

  // ---- anti-phase main loop: A = {M(m); G(m)}, B = {G(m-1); M(m)} ----
  for (int m = 0; m <= 256; ++m) {
    if (ch == 0) { if (m < 256) MPH(m); }
    else         { if (m >= 1)  GPH(m - 1); }
    __syncthreads();
    if (m == 256) break;
    if (ch == 0) GPH(m);
    else         MPH(m);
    __syncthreads();
  }

  #pragma unroll
  for (int jh = 0; jh < 2; ++jh)
    #pragma unroll
    for (int q = 0; q < 4; ++q)
      fout[(row0 + akg * 4 + q) * 128 + jc[jh]] = hst[jh][q];
}

// -------------------- fused attention + MLP -------------------------------
template<int K, int N>
__device__ __forceinline__ void mlp_layer(
    const unsigned short* __restrict__ xin, unsigned short* __restrict__ xout,
    const unsigned short* __restrict__ Wt, const float* __restrict__ bias,
    int lane, int wv, float* __restrict__ foutF)
{
  constexpr int NT = N / 64;
  const int ar  = lane & 15;
  const int akg = lane >> 4;
  f32x4 acc[NT];
  #pragma unroll
  for (int nt = 0; nt < NT; ++nt) acc[nt] = f32x4{0.f, 0.f, 0.f, 0.f};
  for (int ks = 0; ks < K / 32; ++ks) {
    const short8 a = *(const short8*)&xin[ar * 1032 + ks * 32 + akg * 8];
    #pragma unroll
    for (int nt = 0; nt < NT; ++nt) {
      const int n = wv * (N / 4) + nt * 16 + ar;
      const short8 b = *(const short8*)&Wt[n * K + ks * 32 + akg * 8];
      acc[nt] = __builtin_amdgcn_mfma_f32_16x16x32_bf16(a, b, acc[nt], 0, 0, 0);
    }
  }
  const int rbase = akg * 4;
  #pragma unroll
  for (int nt = 0; nt < NT; ++nt) {
    const int n = wv * (N / 4) + nt * 16 + ar;
    const float bv = bias[n];
    #pragma unroll
    for (int q = 0; q < 4; ++q) {
      float v = acc[nt][q] + bv;
      v = fmaxf(v, 0.f);
      xout[(rbase + q) * 1032 + n] = f2bf(v);
      if (foutF) foutF[(rbase + q) * 128 + n] = v;
    }
  }
}

__global__ __launch_bounds__(256) void attn_mlp_kernel(
    const float* __restrict__ fs, const float* __restrict__ fh, const float* __restrict__ fw,
    const float* __restrict__ Wa, const float* __restrict__ ba,
    const unsigned short* __restrict__ Wt,
    const float* __restrict__ b1, const float* __restrict__ b2,
    const float* __restrict__ b3, const float* __restrict__ b4,
    const float* __restrict__ Wo, const float* __restrict__ bo,
    float* __restrict__ out)
{
  __shared__ __align__(16) unsigned short xa[16 * 1032];
  __shared__ __align__(16) unsigned short xb[16 * 1032];
  __shared__ __align__(16) float sf_l[16 * 128];
  __shared__ __align__(16) float x4f[16 * 128];

  const int tid  = threadIdx.x;
  const int lane = tid & 63;
  const int wv   = tid >> 6;
  const int row0 = blockIdx.x * 16;

  {
    const int i  = tid >> 4;
    const int j0 = (tid & 15) * 8;
    float wa[9], bav[3];
    #pragma unroll
    for (int q = 0; q < 9; ++q) wa[q] = Wa[q];
    #pragma unroll
    for (int q = 0; q < 3; ++q) bav[q] = ba[q];
    const int base = (row0 + i) * 128 + j0;
    #pragma unroll
    for (int half = 0; half < 2; ++half) {
      const f32x4 a = *(const f32x4*)&fs[base + half * 4];
      const f32x4 b = *(const f32x4*)&fh[base + half * 4];
      const f32x4 c = *(const f32x4*)&fw[base + half * 4];
      #pragma unroll
      for (int q = 0; q < 4; ++q) {
        const float f0 = a[q], f1 = b[q], f2 = c[q];
        float s0 = f0 * wa[0] + f1 * wa[3] + f2 * wa[6] + bav[0];
        float s1 = f0 * wa[1] + f1 * wa[4] + f2 * wa[7] + bav[1];
        float s2 = f0 * wa[2] + f1 * wa[5] + f2 * wa[8] + bav[2];
        s0 = fmaxf(s0, 0.f); s1 = fmaxf(s1, 0.f); s2 = fmaxf(s2, 0.f);
        const float m  = fmaxf(s0, fmaxf(s1, s2));
        const float e0 = __builtin_amdgcn_exp2f((s0 - m) * LOG2E);
        const float e1 = __builtin_amdgcn_exp2f((s1 - m) * LOG2E);
        const float e2 = __builtin_amdgcn_exp2f((s2 - m) * LOG2E);
        const float inv = __builtin_amdgcn_rcpf(e0 + e1 + e2);
        const float sf  = (f0 * e0 + f1 * e1 + f2 * e2) * inv;
        const int jj = j0 + half * 4 + q;
        sf_l[i * 128 + jj] = sf;
        xa[i * 1032 + jj]  = f2bf(sf);
      }
    }
  }
  __syncthreads();

  mlp_layer<128, 1024>(xa, xb, Wt,          b1, lane, wv, nullptr);
  __syncthreads();
  mlp_layer<1024, 512>(xb, xa, Wt + 131072, b2, lane, wv, nullptr);
  __syncthreads();
  mlp_layer<512,  256>(xa, xb, Wt + 655360, b3, lane, wv, nullptr);
  __syncthreads();
  mlp_layer<256,  128>(xb, xa, Wt + 786432, b4, lane, wv, x4f);
  __syncthreads();

  const int row = tid >> 4;
  const int p   = tid & 15;
  float part = 0.f;
  #pragma unroll
  for (int q = 0; q < 8; ++q) {
    const int jj = p + q * 16;
    part += (x4f[row * 128 + jj] + sf_l[row * 128 + jj]) * Wo[jj];
  }
  #pragma unroll
  for (int off = 8; off > 0; off >>= 1)
    part += __shfl_xor(part, off, 16);
  if (p == 0) out[row0 + row] = part + bo[0];
}

// -------------------- launch ----------------------------------------------
extern "C" void kernel_launch(void* const* d_in, const int* in_sizes, int n_in,
                              void* d_out, int out_size, void* d_ws, size_t ws_size,
                              hipStream_t stream) {
  const float* spatial  = (const float*)d_in[0];
  const int*   hour_idx = (const int*)d_in[1];
  const int*   week_idx = (const int*)d_in[2];
  const float* E_time   = (const float*)d_in[3];
  const float* E_week   = (const float*)d_in[4];
  const float* Ws_x = (const float*)d_in[5];
  const float* Ws_h = (const float*)d_in[6];
  const float* bs   = (const float*)d_in[7];
  const float* Wh_x = (const float*)d_in[8];
  const float* Wh_h = (const float*)d_in[9];
  const float* bh   = (const float*)d_in[10];
  const float* Ww_x = (const float*)d_in[11];
  const float* Ww_h = (const float*)d_in[12];
  const float* bw   = (const float*)d_in[13];
  const float* Wa   = (const float*)d_in[14];
  const float* ba   = (const float*)d_in[15];
  const float* W1   = (const float*)d_in[16];
  const float* b1   = (const float*)d_in[17];
  const float* W2   = (const float*)d_in[18];
  const float* b2   = (const float*)d_in[19];
  const float* W3   = (const float*)d_in[20];
  const float* b3   = (const float*)d_in[21];
  const float* W4   = (const float*)d_in[22];
  const float* b4   = (const float*)d_in[23];
  const float* Wo   = (const float*)d_in[24];
  const float* bo   = (const float*)d_in[25];
  float* out = (float*)d_out;

  float* ws    = (float*)d_ws;
  float* Ptime = ws;                     // 24*384
  float* Pweek = Ptime + 9216;           // 7*384
  float* fsb   = Pweek + 2688;           // 1024*128
  float* fhb   = fsb + 131072;
  float* fwb   = fhb + 131072;
  unsigned short* Wt = (unsigned short*)(fwb + 131072);  // 819200 bf16

  ptab_kernel<<<31, 256, 0, stream>>>(E_time, E_week, Wh_x, bh, Ww_x, bw, Ptime, Pweek);
  gru_kernel<<<296, 512, 0, stream>>>(spatial, hour_idx, week_idx, Ws_x,
      Ws_h, bs, Wh_h, bh, Ww_h, bw, Ptime, Pweek,
      W1, W2, W3, W4, Wt, fsb, fhb, fwb);
  attn_mlp_kernel<<<64, 256, 0, stream>>>(fsb, fhb, fwb, Wa, ba, Wt,
      b1, b2, b3, b4, Wo, bo, out);
}

// Round 8
// 240.108 us; speedup vs baseline: 1.9676x; 1.9676x over previous
//
#include <hip/hip_runtime.h>
#include <hip/hip_bf16.h>

typedef __attribute__((ext_vector_type(8))) short short8;
typedef __attribute__((ext_vector_type(4))) float f32x4;
typedef __attribute__((ext_vector_type(2))) float f32x2;

#define LOG2E  1.44269504088896340736f
#define NLOG2E (-1.44269504088896340736f)
#define TLOG2E (2.88539008177792681472f)

#define HES 168   // h_ext row stride in shorts: 84 dw == 20 mod 32 -> 2-way (free) on b128

__device__ __forceinline__ unsigned short f2bf(float f) {
  unsigned u = __builtin_bit_cast(unsigned, f);
  u += 0x7fffu + ((u >> 16) & 1u);
  return (unsigned short)(u >> 16);
}

// -------------------- setup: P tables + tiled MLP weight transpose --------
// blocks 0..30: ptab rows. blocks 31..230: 64x64 transpose tiles (both sides
// coalesced via LDS tile). Validated in R5.
__global__ __launch_bounds__(256) void setup_kernel(
    const float* __restrict__ E_time, const float* __restrict__ E_week,
    const float* __restrict__ Wh_x, const float* __restrict__ bh,
    const float* __restrict__ Ww_x, const float* __restrict__ bw,
    const float* __restrict__ W1, const float* __restrict__ W2,
    const float* __restrict__ W3, const float* __restrict__ W4,
    float* __restrict__ Ptime, float* __restrict__ Pweek,
    unsigned short* __restrict__ Wt)
{
  const int b = blockIdx.x;
  const int tid = threadIdx.x;
  if (b < 31) {
    for (int c = tid; c < 384; c += 256) {
      if (b < 24) {
        float acc = bh[c];
        for (int d = 0; d < 128; ++d)
          acc = fmaf(E_time[b * 128 + d], Wh_x[d * 384 + c], acc);
        Ptime[b * 384 + c] = acc;
      } else {
        const int r = b - 24;
        float acc = bw[c];
        for (int d = 0; d < 128; ++d)
          acc = fmaf(E_week[r * 128 + d], Ww_x[d * 384 + c], acc);
        Pweek[r * 384 + c] = acc;
      }
    }
    return;
  }
  __shared__ float tile[64][65];
  int tb = b - 31;
  const float* src; unsigned short* dst; int K, N, tk, tn;
  if (tb < 32)       { src = W1; dst = Wt;          K = 128;  N = 1024; tk = tb >> 4; tn = tb & 15; }
  else if (tb < 160) { tb -= 32;  src = W2; dst = Wt + 131072; K = 1024; N = 512;  tk = tb >> 3; tn = tb & 7; }
  else if (tb < 192) { tb -= 160; src = W3; dst = Wt + 655360; K = 512;  N = 256;  tk = tb >> 2; tn = tb & 3; }
  else               { tb -= 192; src = W4; dst = Wt + 786432; K = 256;  N = 128;  tk = tb >> 1; tn = tb & 1; }
  const int tx = tid & 63, ty = tid >> 6;
  const int k0 = tk * 64, n0 = tn * 64;
  #pragma unroll
  for (int i = 0; i < 16; ++i)
    tile[ty * 16 + i][tx] = src[(k0 + ty * 16 + i) * N + n0 + tx];
  __syncthreads();
  #pragma unroll
  for (int i = 0; i < 16; ++i)
    dst[(n0 + ty * 16 + i) * K + k0 + tx] = f2bf(tile[tx][ty * 16 + i]);
}

// -------------------- persistent GRU kernel v8 (= v4 + merged-rcp gates) --
// grid 192 = 3 GRUs x 64 chunks of 16 rows. 512 threads = 8 waves.
// Wave wv owns cols j = wv*16+ar for gates z/r/nh/nx (15 MFMA). x-projection
// folded into extension rows of the K dim. Gates pure-register, merged rcp.
__global__ __launch_bounds__(512, 2) void gru_kernel(
    const float* __restrict__ spatial,
    const int* __restrict__ hour_idx,
    const int* __restrict__ week_idx,
    const float* __restrict__ Ws_x,
    const float* __restrict__ Ws_h, const float* __restrict__ bs,
    const float* __restrict__ Wh_h, const float* __restrict__ bh,
    const float* __restrict__ Ww_h, const float* __restrict__ bw,
    const float* __restrict__ Ptime, const float* __restrict__ Pweek,
    float* __restrict__ fs, float* __restrict__ fh, float* __restrict__ fw)
{
  __shared__ __align__(16) unsigned short hx[2][16 * HES];

  const int tid  = threadIdx.x;
  const int lane = tid & 63;
  const int wv   = tid >> 6;       // 0..7
  const int ar   = lane & 15;
  const int akg  = lane >> 4;      // 0..3
  const int gid  = blockIdx.x;
  const int gru  = gid >> 6;
  const int row0 = (gid & 63) * 16;

  const float* __restrict__ Wh   = (gru == 0) ? Ws_h : (gru == 1) ? Wh_h : Ww_h;
  const float* __restrict__ bvec = (gru == 0) ? bs   : (gru == 1) ? bh   : bw;
  float* __restrict__ fout       = (gru == 0) ? fs   : (gru == 1) ? fh   : fw;
  const float* __restrict__ Ptab = (gru == 1) ? Ptime : Pweek;
  const int* __restrict__ idxg   = (gru == 1) ? hour_idx : week_idx;
  const int NR = (gru == 1) ? 24 : 7;

  const int j = wv * 16 + ar;      // owned hidden col

  // ---- weight fragments: wf[0..4]=z(ks0..4), wf[5..9]=r, wf[10..13]=nh, wf[14]=nx
  short8 wf[15];
  #pragma unroll
  for (int g = 0; g < 2; ++g) {
    #pragma unroll
    for (int ks = 0; ks < 5; ++ks) {
      short8 f;
      #pragma unroll
      for (int q = 0; q < 8; ++q) {
        const int k = ks * 32 + akg * 8 + q;
        float v;
        if (k < 128) v = Wh[k * 384 + g * 128 + j];
        else {
          const int p = k - 128;
          if (gru == 0) v = (p == 0) ? Ws_x[g * 128 + j]
                          : (p == 1) ? Ws_x[384 + g * 128 + j] : 0.f;
          else          v = (p < NR) ? Ptab[p * 384 + g * 128 + j] : 0.f;
        }
        f[q] = (short)f2bf(v * NLOG2E);
      }
      wf[g * 5 + ks] = f;
    }
  }
  #pragma unroll
  for (int ks = 0; ks < 4; ++ks) {   // nh (h-side only, K=128)
    short8 f;
    #pragma unroll
    for (int q = 0; q < 8; ++q) {
      const int k = ks * 32 + akg * 8 + q;
      f[q] = (short)f2bf(Wh[k * 384 + 256 + j] * TLOG2E);
    }
    wf[10 + ks] = f;
  }
  {                                  // nx (extension rows only)
    short8 f;
    #pragma unroll
    for (int q = 0; q < 8; ++q) {
      const int p = akg * 8 + q;
      float v;
      if (gru == 0) v = (p == 0) ? Ws_x[256 + j]
                      : (p == 1) ? Ws_x[384 + 256 + j] : 0.f;
      else          v = (p < NR) ? Ptab[p * 384 + 256 + j] : 0.f;
      f[q] = (short)f2bf(v * TLOG2E);
    }
    wf[14] = f;
  }

  // exact fp32 biases in accumulator init (b0 for gru1/2 lives inside P)
  const float bz  = (bvec[384 + j]       + (gru == 0 ? bvec[j]       : 0.f)) * NLOG2E;
  const float br  = (bvec[384 + 128 + j] + (gru == 0 ? bvec[128 + j] : 0.f)) * NLOG2E;
  const float bnh = bvec[384 + 256 + j] * TLOG2E;
  const float bnx = (gru == 0 ? bvec[256 + j] : 0.f) * TLOG2E;

  // ---- zero both h_ext buffers, then place step-0 extension values ----
  for (int e = tid; e < 2 * 16 * HES; e += 512) ((unsigned short*)hx)[e] = 0;
  __syncthreads();

  const bool mt  = (tid & 31) == 0;  // 16 maintenance threads, 2 per wave
  const int mrow = tid >> 5;
  int ix_prev = 0, ix_cur = 0;
  if (mt) {
    if (gru == 0) {
      const f32x2 s = *(const f32x2*)&spatial[(row0 + mrow) * 512];
      unsigned pk;
      asm("v_cvt_pk_bf16_f32 %0, %1, %2" : "=v"(pk) : "v"(s.x), "v"(s.y));
      *(unsigned*)&hx[0][mrow * HES + 128] = pk;
    } else {
      ix_cur = idxg[(row0 + mrow) * 256];
      hx[0][mrow * HES + 128 + ix_cur] = 0x3F80;   // bf16 1.0
    }
  }
  __syncthreads();

  float hst[4] = {0.f, 0.f, 0.f, 0.f};

  for (int t = 0; t < 256; ++t) {
    const unsigned short* __restrict__ hb = hx[t & 1];
    unsigned short* __restrict__ ho       = hx[(t + 1) & 1];

    // ---- A-fragments FIRST (MFMA-critical; nothing ahead in the LDS queue)
    short8 a[5];
    #pragma unroll
    for (int ks = 0; ks < 5; ++ks)
      a[ks] = *(const short8*)&hb[ar * HES + ks * 32 + akg * 8];

    // ---- maintenance global prefetch for t+1 (vmcnt queue, overlaps MFMA)
    f32x2 msp = {0.f, 0.f};
    int ix_next = 0;
    const bool mact = mt && (t + 1 < 256);
    if (mact) {
      if (gru == 0) msp = *(const f32x2*)&spatial[(row0 + mrow) * 512 + 2 * (t + 1)];
      else          ix_next = idxg[(row0 + mrow) * 256 + t + 1];
    }

    // ---- MFMA: complete pre-activations (x-part via extension rows) ----
    f32x4 az  = {bz, bz, bz, bz};
    f32x4 arr = {br, br, br, br};
    f32x4 anh = {bnh, bnh, bnh, bnh};
    f32x4 anx = {bnx, bnx, bnx, bnx};
    #pragma unroll
    for (int ks = 0; ks < 4; ++ks) {
      az  = __builtin_amdgcn_mfma_f32_16x16x32_bf16(a[ks], wf[ks],      az,  0, 0, 0);
      arr = __builtin_amdgcn_mfma_f32_16x16x32_bf16(a[ks], wf[5 + ks],  arr, 0, 0, 0);
      anh = __builtin_amdgcn_mfma_f32_16x16x32_bf16(a[ks], wf[10 + ks], anh, 0, 0, 0);
    }
    az  = __builtin_amdgcn_mfma_f32_16x16x32_bf16(a[4], wf[4],  az,  0, 0, 0);
    arr = __builtin_amdgcn_mfma_f32_16x16x32_bf16(a[4], wf[9],  arr, 0, 0, 0);
    anx = __builtin_amdgcn_mfma_f32_16x16x32_bf16(a[4], wf[14], anx, 0, 0, 0);

    // ---- maintenance: write extension values for t+1 into target buffer
    if (mact) {
      if (gru == 0) {
        unsigned pk;
        asm("v_cvt_pk_bf16_f32 %0, %1, %2" : "=v"(pk) : "v"(msp.x), "v"(msp.y));
        *(unsigned*)&ho[mrow * HES + 128] = pk;
      } else {
        if (t >= 1) ho[mrow * HES + 128 + ix_prev] = 0;       // clear onehot(t-1)
        ho[mrow * HES + 128 + ix_next] = 0x3F80;              // set onehot(t+1)
        ix_prev = ix_cur; ix_cur = ix_next;
      }
    }

    // ---- gates: pure-register, merged rcp (trans 24 -> 16) ----
    float pz[4], pr[4];
    #pragma unroll
    for (int q = 0; q < 4; ++q) {
      pz[q] = 1.f + __builtin_amdgcn_exp2f(az[q]);
      pr[q] = 1.f + __builtin_amdgcn_exp2f(arr[q]);
    }
    float zg[4], rg[4];
    #pragma unroll
    for (int p = 0; p < 4; p += 2) {
      const float A0 = pz[p] * pr[p];
      const float A1 = pz[p + 1] * pr[p + 1];
      const float inv = __builtin_amdgcn_rcpf(A0 * A1);
      const float t1 = A1 * inv, t0 = A0 * inv;
      zg[p]     = pr[p] * t1;     rg[p]     = pz[p] * t1;
      zg[p + 1] = pr[p + 1] * t0; rg[p + 1] = pz[p + 1] * t0;
    }
    float ph[4];
    #pragma unroll
    for (int q = 0; q < 4; ++q)
      ph[q] = 1.f + __builtin_amdgcn_exp2f(fmaf(rg[q], anh[q], anx[q]));
    float hn4[4];
    #pragma unroll
    for (int p = 0; p < 4; p += 2) {
      const float inv = __builtin_amdgcn_rcpf(ph[p] * ph[p + 1]);
      const float hh0 = fmaf(-2.f, ph[p + 1] * inv, 1.f);
      const float hh1 = fmaf(-2.f, ph[p] * inv, 1.f);
      hn4[p]     = fmaf(zg[p],     hst[p]     - hh0, hh0);
      hn4[p + 1] = fmaf(zg[p + 1], hst[p + 1] - hh1, hh1);
      hst[p] = hn4[p]; hst[p + 1] = hn4[p + 1];
    }

    // ---- write h(t+1) ----
    #pragma unroll
    for (int q = 0; q < 4; ++q)
      ho[(akg * 4 + q) * HES + j] = f2bf(hn4[q]);

    __syncthreads();
  }

  #pragma unroll
  for (int q = 0; q < 4; ++q)
    fout[(row0 + akg * 4 + q) * 128 + j] = hst[q];
}

// -------------------- fused attention + MLP -------------------------------
template<int K, int N>
__device__ __forceinline__ void mlp_layer(
    const unsigned short* __restrict__ xin, unsigned short* __restrict__ xout,
    const unsigned short* __restrict__ Wt, const float* __restrict__ bias,
    int lane, int wv, float* __restrict__ foutF)
{
  constexpr int NT = N / 64;
  const int ar  = lane & 15;
  const int akg = lane >> 4;
  f32x4 acc[NT];
  #pragma unroll
  for (int nt = 0; nt < NT; ++nt) acc[nt] = f32x4{0.f, 0.f, 0.f, 0.f};
  for (int ks = 0; ks < K / 32; ++ks) {
    const short8 a = *(const short8*)&xin[ar * 1032 + ks * 32 + akg * 8];
    #pragma unroll
    for (int nt = 0; nt < NT; ++nt) {
      const int n = wv * (N / 4) + nt * 16 + ar;
      const short8 b = *(const short8*)&Wt[n * K + ks * 32 + akg * 8];
      acc[nt] = __builtin_amdgcn_mfma_f32_16x16x32_bf16(a, b, acc[nt], 0, 0, 0);
    }
  }
  const int rbase = akg * 4;
  #pragma unroll
  for (int nt = 0; nt < NT; ++nt) {
    const int n = wv * (N / 4) + nt * 16 + ar;
    const float bv = bias[n];
    #pragma unroll
    for (int q = 0; q < 4; ++q) {
      float v = acc[nt][q] + bv;
      v = fmaxf(v, 0.f);
      xout[(rbase + q) * 1032 + n] = f2bf(v);
      if (foutF) foutF[(rbase + q) * 128 + n] = v;
    }
  }
}

__global__ __launch_bounds__(256) void attn_mlp_kernel(
    const float* __restrict__ fs, const float* __restrict__ fh, const float* __restrict__ fw,
    const float* __restrict__ Wa, const float* __restrict__ ba,
    const unsigned short* __restrict__ Wt,
    const float* __restrict__ b1, const float* __restrict__ b2,
    const float* __restrict__ b3, const float* __restrict__ b4,
    const float* __restrict__ Wo, const float* __restrict__ bo,
    float* __restrict__ out)
{
  __shared__ __align__(16) unsigned short xa[16 * 1032];
  __shared__ __align__(16) unsigned short xb[16 * 1032];
  __shared__ __align__(16) float sf_l[16 * 128];
  __shared__ __align__(16) float x4f[16 * 128];

  const int tid  = threadIdx.x;
  const int lane = tid & 63;
  const int wv   = tid >> 6;
  const int row0 = blockIdx.x * 16;

  {
    const int i  = tid >> 4;
    const int j0 = (tid & 15) * 8;
    float wa[9], bav[3];
    #pragma unroll
    for (int q = 0; q < 9; ++q) wa[q] = Wa[q];
    #pragma unroll
    for (int q = 0; q < 3; ++q) bav[q] = ba[q];
    const int base = (row0 + i) * 128 + j0;
    #pragma unroll
    for (int half = 0; half < 2; ++half) {
      const f32x4 a = *(const f32x4*)&fs[base + half * 4];
      const f32x4 b = *(const f32x4*)&fh[base + half * 4];
      const f32x4 c = *(const f32x4*)&fw[base + half * 4];
      #pragma unroll
      for (int q = 0; q < 4; ++q) {
        const float f0 = a[q], f1 = b[q], f2 = c[q];
        float s0 = f0 * wa[0] + f1 * wa[3] + f2 * wa[6] + bav[0];
        float s1 = f0 * wa[1] + f1 * wa[4] + f2 * wa[7] + bav[1];
        float s2 = f0 * wa[2] + f1 * wa[5] + f2 * wa[8] + bav[2];
        s0 = fmaxf(s0, 0.f); s1 = fmaxf(s1, 0.f); s2 = fmaxf(s2, 0.f);
        const float m  = fmaxf(s0, fmaxf(s1, s2));
        const float e0 = __builtin_amdgcn_exp2f((s0 - m) * LOG2E);
        const float e1 = __builtin_amdgcn_exp2f((s1 - m) * LOG2E);
        const float e2 = __builtin_amdgcn_exp2f((s2 - m) * LOG2E);
        const float inv = __builtin_amdgcn_rcpf(e0 + e1 + e2);
        const float sf  = (f0 * e0 + f1 * e1 + f2 * e2) * inv;
        const int jj = j0 + half * 4 + q;
        sf_l[i * 128 + jj] = sf;
        xa[i * 1032 + jj]  = f2bf(sf);
      }
    }
  }
  __syncthreads();

  mlp_layer<128, 1024>(xa, xb, Wt,          b1, lane, wv, nullptr);
  __syncthreads();
  mlp_layer<1024, 512>(xb, xa, Wt + 131072, b2, lane, wv, nullptr);
  __syncthreads();
  mlp_layer<512,  256>(xa, xb, Wt + 655360, b3, lane, wv, nullptr);
  __syncthreads();
  mlp_layer<256,  128>(xb, xa, Wt + 786432, b4, lane, wv, x4f);
  __syncthreads();

  const int row = tid >> 4;
  const int p   = tid & 15;
  float part = 0.f;
  #pragma unroll
  for (int q = 0; q < 8; ++q) {
    const int jj = p + q * 16;
    part += (x4f[row * 128 + jj] + sf_l[row * 128 + jj]) * Wo[jj];
  }
  #pragma unroll
  for (int off = 8; off > 0; off >>= 1)
    part += __shfl_xor(part, off, 16);
  if (p == 0) out[row0 + row] = part + bo[0];
}

// -------------------- launch ----------------------------------------------
extern "C" void kernel_launch(void* const* d_in, const int* in_sizes, int n_in,
                              void* d_out, int out_size, void* d_ws, size_t ws_size,
                              hipStream_t stream) {
  const float* spatial  = (const float*)d_in[0];
  const int*   hour_idx = (const int*)d_in[1];
  const int*   week_idx = (const int*)d_in[2];
  const float* E_time   = (const float*)d_in[3];
  const float* E_week   = (const float*)d_in[4];
  const float* Ws_x = (const float*)d_in[5];
  const float* Ws_h = (const float*)d_in[6];
  const float* bs   = (const float*)d_in[7];
  const float* Wh_x = (const float*)d_in[8];
  const float* Wh_h = (const float*)d_in[9];
  const float* bh   = (const float*)d_in[10];
  const float* Ww_x = (const float*)d_in[11];
  const float* Ww_h = (const float*)d_in[12];
  const float* bw   = (const float*)d_in[13];
  const float* Wa   = (const float*)d_in[14];
  const float* ba   = (const float*)d_in[15];
  const float* W1   = (const float*)d_in[16];
  const float* b1   = (const float*)d_in[17];
  const float* W2   = (const float*)d_in[18];
  const float* b2   = (const float*)d_in[19];
  const float* W3   = (const float*)d_in[20];
  const float* b3   = (const float*)d_in[21];
  const float* W4   = (const float*)d_in[22];
  const float* b4   = (const float*)d_in[23];
  const float* Wo   = (const float*)d_in[24];
  const float* bo   = (const float*)d_in[25];
  float* out = (float*)d_out;

  float* ws    = (float*)d_ws;
  float* Ptime = ws;                     // 24*384
  float* Pweek = Ptime + 9216;           // 7*384
  float* fsb   = Pweek + 2688;           // 1024*128
  float* fhb   = fsb + 131072;
  float* fwb   = fhb + 131072;
  unsigned short* Wt = (unsigned short*)(fwb + 131072);  // 819200 bf16

  setup_kernel<<<231, 256, 0, stream>>>(E_time, E_week, Wh_x, bh, Ww_x, bw,
      W1, W2, W3, W4, Ptime, Pweek, Wt);
  gru_kernel<<<192, 512, 0, stream>>>(spatial, hour_idx, week_idx, Ws_x,
      Ws_h, bs, Wh_h, bh, Ww_h, bw, Ptime, Pweek, fsb, fhb, fwb);
  attn_mlp_kernel<<<64, 256, 0, stream>>>(fsb, fhb, fwb, Wa, ba, Wt,
      b1, b2, b3, b4, Wo, bo, out);
}

// Round 9
// 230.484 us; speedup vs baseline: 2.0498x; 1.0418x over previous
//
#include <hip/hip_runtime.h>
#include <hip/hip_bf16.h>

typedef __attribute__((ext_vector_type(8))) short short8;
typedef __attribute__((ext_vector_type(4))) float f32x4;
typedef __attribute__((ext_vector_type(2))) float f32x2;
typedef __attribute__((ext_vector_type(2))) unsigned u32x2;

#define LOG2E  1.44269504088896340736f
#define NLOG2E (-1.44269504088896340736f)
#define TLOG2E (2.88539008177792681472f)

#define HES 168   // h_ext row stride in shorts: 84 dw == 20 mod 32 -> 2-way (free) on b128

__device__ __forceinline__ unsigned short f2bf(float f) {
  unsigned u = __builtin_bit_cast(unsigned, f);
  u += 0x7fffu + ((u >> 16) & 1u);
  return (unsigned short)(u >> 16);
}

// -------------------- setup: P tables only --------------------------------
__global__ __launch_bounds__(256) void ptab_kernel(
    const float* __restrict__ E_time, const float* __restrict__ E_week,
    const float* __restrict__ Wh_x, const float* __restrict__ bh,
    const float* __restrict__ Ww_x, const float* __restrict__ bw,
    float* __restrict__ Ptime, float* __restrict__ Pweek)
{
  const int b = blockIdx.x;
  for (int c = threadIdx.x; c < 384; c += 256) {
    if (b < 24) {
      float acc = bh[c];
      for (int d = 0; d < 128; ++d)
        acc = fmaf(E_time[b * 128 + d], Wh_x[d * 384 + c], acc);
      Ptime[b * 384 + c] = acc;
    } else {
      const int r = b - 24;
      float acc = bw[c];
      for (int d = 0; d < 128; ++d)
        acc = fmaf(E_week[r * 128 + d], Ww_x[d * 384 + c], acc);
      Pweek[r * 384 + c] = acc;
    }
  }
}

// -------------------- persistent GRU kernel v9 (transposed MFMA) ----------
// grid 192 = 3 GRUs x 64 chunks of 16 rows. 512 threads = 8 waves.
// hp^T = Wext^T . h^T: A-frag = weights (registers), B-frag = h (LDS reads,
// addresses identical to v8). C layout: lane&15 = batch row, (lane>>4)*4+q =
// 4 CONSECUTIVE h-cols -> h-write is ONE ds_write_b64/thread (was 4x b16),
// fout is one global_store_dwordx4. Gate math identical to v8 (merged rcp).
// Tail: MLP weight transpose tiles reuse the smem (frees the setup kernel).
__global__ __launch_bounds__(512, 2) void gru_kernel(
    const float* __restrict__ spatial,
    const int* __restrict__ hour_idx,
    const int* __restrict__ week_idx,
    const float* __restrict__ Ws_x,
    const float* __restrict__ Ws_h, const float* __restrict__ bs,
    const float* __restrict__ Wh_h, const float* __restrict__ bh,
    const float* __restrict__ Ww_h, const float* __restrict__ bw,
    const float* __restrict__ Ptime, const float* __restrict__ Pweek,
    const float* __restrict__ W1, const float* __restrict__ W2,
    const float* __restrict__ W3, const float* __restrict__ W4,
    unsigned short* __restrict__ Wt,
    float* __restrict__ fs, float* __restrict__ fh, float* __restrict__ fw)
{
  __shared__ __align__(16) unsigned char smem_u[64 * 65 * 4];  // 16.6 KB union
  unsigned short (*hx)[16 * HES] = (unsigned short (*)[16 * HES])smem_u;

  const int tid  = threadIdx.x;
  const int lane = tid & 63;
  const int wv   = tid >> 6;       // 0..7
  const int ar   = lane & 15;      // dual role: wf out-col within tile; batch row for B/C
  const int akg  = lane >> 4;      // 0..3
  const int gid  = blockIdx.x;
  const int gru  = gid >> 6;
  const int row0 = (gid & 63) * 16;

  const float* __restrict__ Wh   = (gru == 0) ? Ws_h : (gru == 1) ? Wh_h : Ww_h;
  const float* __restrict__ bvec = (gru == 0) ? bs   : (gru == 1) ? bh   : bw;
  float* __restrict__ fout       = (gru == 0) ? fs   : (gru == 1) ? fh   : fw;
  const float* __restrict__ Ptab = (gru == 1) ? Ptime : Pweek;
  const int* __restrict__ idxg   = (gru == 1) ? hour_idx : week_idx;
  const int NR = (gru == 1) ? 24 : 7;

  const int j  = wv * 16 + ar;     // wf build col (A out-col = lane&15)
  const int c4 = wv * 16 + akg * 4;// this lane's 4 owned h-cols (C rows)

  // ---- A-operand weight fragments (same build expression as v8's B-frags):
  // wf[0..4]=z(ks0..4), wf[5..9]=r, wf[10..13]=nh, wf[14]=nx
  short8 wf[15];
  #pragma unroll
  for (int g = 0; g < 2; ++g) {
    #pragma unroll
    for (int ks = 0; ks < 5; ++ks) {
      short8 f;
      #pragma unroll
      for (int q = 0; q < 8; ++q) {
        const int k = ks * 32 + akg * 8 + q;
        float v;
        if (k < 128) v = Wh[k * 384 + g * 128 + j];
        else {
          const int p = k - 128;
          if (gru == 0) v = (p == 0) ? Ws_x[g * 128 + j]
                          : (p == 1) ? Ws_x[384 + g * 128 + j] : 0.f;
          else          v = (p < NR) ? Ptab[p * 384 + g * 128 + j] : 0.f;
        }
        f[q] = (short)f2bf(v * NLOG2E);
      }
      wf[g * 5 + ks] = f;
    }
  }
  #pragma unroll
  for (int ks = 0; ks < 4; ++ks) {   // nh (h-side only, K=128)
    short8 f;
    #pragma unroll
    for (int q = 0; q < 8; ++q) {
      const int k = ks * 32 + akg * 8 + q;
      f[q] = (short)f2bf(Wh[k * 384 + 256 + j] * TLOG2E);
    }
    wf[10 + ks] = f;
  }
  {                                  // nx (extension rows only)
    short8 f;
    #pragma unroll
    for (int q = 0; q < 8; ++q) {
      const int p = akg * 8 + q;
      float v;
      if (gru == 0) v = (p == 0) ? Ws_x[256 + j]
                      : (p == 1) ? Ws_x[384 + 256 + j] : 0.f;
      else          v = (p < NR) ? Ptab[p * 384 + 256 + j] : 0.f;
      f[q] = (short)f2bf(v * TLOG2E);
    }
    wf[14] = f;
  }

  // ---- bias vectors for the 4 owned cols (exact fp32, in accumulator init)
  f32x4 bzv, brv, bnhv, bnxv;
  {
    const f32x4 z1 = *(const f32x4*)&bvec[384 + c4];
    const f32x4 r1 = *(const f32x4*)&bvec[384 + 128 + c4];
    const f32x4 n1 = *(const f32x4*)&bvec[384 + 256 + c4];
    if (gru == 0) {
      const f32x4 z0 = *(const f32x4*)&bvec[c4];
      const f32x4 r0 = *(const f32x4*)&bvec[128 + c4];
      const f32x4 n0 = *(const f32x4*)&bvec[256 + c4];
      bzv = (z1 + z0) * NLOG2E; brv = (r1 + r0) * NLOG2E;
      bnhv = n1 * TLOG2E;       bnxv = n0 * TLOG2E;
    } else {
      bzv = z1 * NLOG2E; brv = r1 * NLOG2E;
      bnhv = n1 * TLOG2E; bnxv = f32x4{0.f, 0.f, 0.f, 0.f};
    }
  }

  // ---- zero both h_ext buffers, place step-0 extension values ----
  for (int e = tid; e < 2 * 16 * HES; e += 512) ((unsigned short*)hx)[e] = 0;
  __syncthreads();

  const bool mt  = (tid & 31) == 0;  // 16 maintenance threads, 2 per wave
  const int mrow = tid >> 5;
  int ix_prev = 0, ix_cur = 0;
  if (mt) {
    if (gru == 0) {
      const f32x2 s = *(const f32x2*)&spatial[(row0 + mrow) * 512];
      unsigned pk;
      asm("v_cvt_pk_bf16_f32 %0, %1, %2" : "=v"(pk) : "v"(s.x), "v"(s.y));
      *(unsigned*)&hx[0][mrow * HES + 128] = pk;
    } else {
      ix_cur = idxg[(row0 + mrow) * 256];
      hx[0][mrow * HES + 128 + ix_cur] = 0x3F80;   // bf16 1.0
    }
  }
  __syncthreads();

  float hst[4] = {0.f, 0.f, 0.f, 0.f};

  for (int t = 0; t < 256; ++t) {
    const unsigned short* __restrict__ hb = hx[t & 1];
    unsigned short* __restrict__ ho       = hx[(t + 1) & 1];

    // ---- B-fragments (h^T) FIRST: addresses identical to v8's A reads ----
    short8 b[5];
    #pragma unroll
    for (int ks = 0; ks < 5; ++ks)
      b[ks] = *(const short8*)&hb[ar * HES + ks * 32 + akg * 8];

    // ---- maintenance global prefetch for t+1 (overlaps MFMA) ----
    f32x2 msp = {0.f, 0.f};
    int ix_next = 0;
    const bool mact = mt && (t + 1 < 256);
    if (mact) {
      if (gru == 0) msp = *(const f32x2*)&spatial[(row0 + mrow) * 512 + 2 * (t + 1)];
      else          ix_next = idxg[(row0 + mrow) * 256 + t + 1];
    }

    // ---- MFMA: hp^T = Wext^T . h^T (A=weights, B=h) ----
    f32x4 az  = bzv;
    f32x4 arr = brv;
    f32x4 anh = bnhv;
    f32x4 anx = bnxv;
    #pragma unroll
    for (int ks = 0; ks < 4; ++ks) {
      az  = __builtin_amdgcn_mfma_f32_16x16x32_bf16(wf[ks],      b[ks], az,  0, 0, 0);
      arr = __builtin_amdgcn_mfma_f32_16x16x32_bf16(wf[5 + ks],  b[ks], arr, 0, 0, 0);
      anh = __builtin_amdgcn_mfma_f32_16x16x32_bf16(wf[10 + ks], b[ks], anh, 0, 0, 0);
    }
    az  = __builtin_amdgcn_mfma_f32_16x16x32_bf16(wf[4],  b[4], az,  0, 0, 0);
    arr = __builtin_amdgcn_mfma_f32_16x16x32_bf16(wf[9],  b[4], arr, 0, 0, 0);
    anx = __builtin_amdgcn_mfma_f32_16x16x32_bf16(wf[14], b[4], anx, 0, 0, 0);

    // ---- maintenance: extension values for t+1 into target buffer ----
    if (mact) {
      if (gru == 0) {
        unsigned pk;
        asm("v_cvt_pk_bf16_f32 %0, %1, %2" : "=v"(pk) : "v"(msp.x), "v"(msp.y));
        *(unsigned*)&ho[mrow * HES + 128] = pk;
      } else {
        if (t >= 1) ho[mrow * HES + 128 + ix_prev] = 0;       // clear onehot(t-1)
        ho[mrow * HES + 128 + ix_next] = 0x3F80;              // set onehot(t+1)
        ix_prev = ix_cur; ix_cur = ix_next;
      }
    }

    // ---- gates: pure-register, merged rcp (identical math to v8) ----
    float pz[4], pr[4];
    #pragma unroll
    for (int q = 0; q < 4; ++q) {
      pz[q] = 1.f + __builtin_amdgcn_exp2f(az[q]);
      pr[q] = 1.f + __builtin_amdgcn_exp2f(arr[q]);
    }
    float zg[4], rg[4];
    #pragma unroll
    for (int p = 0; p < 4; p += 2) {
      const float A0 = pz[p] * pr[p];
      const float A1 = pz[p + 1] * pr[p + 1];
      const float inv = __builtin_amdgcn_rcpf(A0 * A1);
      const float t1 = A1 * inv, t0 = A0 * inv;
      zg[p]     = pr[p] * t1;     rg[p]     = pz[p] * t1;
      zg[p + 1] = pr[p + 1] * t0; rg[p + 1] = pz[p + 1] * t0;
    }
    float ph[4];
    #pragma unroll
    for (int q = 0; q < 4; ++q)
      ph[q] = 1.f + __builtin_amdgcn_exp2f(fmaf(rg[q], anh[q], anx[q]));
    float hn4[4];
    #pragma unroll
    for (int p = 0; p < 4; p += 2) {
      const float inv = __builtin_amdgcn_rcpf(ph[p] * ph[p + 1]);
      const float hh0 = fmaf(-2.f, ph[p + 1] * inv, 1.f);
      const float hh1 = fmaf(-2.f, ph[p] * inv, 1.f);
      hn4[p]     = fmaf(zg[p],     hst[p]     - hh0, hh0);
      hn4[p + 1] = fmaf(zg[p + 1], hst[p + 1] - hh1, hh1);
      hst[p] = hn4[p]; hst[p + 1] = hn4[p + 1];
    }

    // ---- write h(t+1): 4 consecutive cols, same batch row -> ONE b64 ----
    unsigned p01, p23;
    asm("v_cvt_pk_bf16_f32 %0, %1, %2" : "=v"(p01) : "v"(hn4[0]), "v"(hn4[1]));
    asm("v_cvt_pk_bf16_f32 %0, %1, %2" : "=v"(p23) : "v"(hn4[2]), "v"(hn4[3]));
    *(u32x2*)&ho[ar * HES + c4] = u32x2{p01, p23};

    __syncthreads();
  }

  // ---- final feature store: one dwordx4 per thread ----
  {
    const f32x4 v = {hst[0], hst[1], hst[2], hst[3]};
    *(f32x4*)&fout[(row0 + ar) * 128 + c4] = v;
  }

  // ================= tail: MLP weight transpose (reuses smem) =============
  __syncthreads();
  float (*ttile)[65] = (float (*)[65])smem_u;
  const int tx = tid & 63, ty = tid >> 6;      // ty 0..7
  for (int t0 = blockIdx.x; t0 < 200; t0 += 192) {
    int tb = t0;
    const float* src; unsigned short* dst; int K, N, tk, tn;
    if (tb < 32)       { src = W1; dst = Wt;          K = 128;  N = 1024; tk = tb >> 4; tn = tb & 15; }
    else if (tb < 160) { tb -= 32;  src = W2; dst = Wt + 131072; K = 1024; N = 512;  tk = tb >> 3; tn = tb & 7; }
    else if (tb < 192) { tb -= 160; src = W3; dst = Wt + 655360; K = 512;  N = 256;  tk = tb >> 2; tn = tb & 3; }
    else               { tb -= 192; src = W4; dst = Wt + 786432; K = 256;  N = 128;  tk = tb >> 1; tn = tb & 1; }
    const int k0 = tk * 64, n0 = tn * 64;
    #pragma unroll
    for (int i = 0; i < 8; ++i)
      ttile[ty * 8 + i][tx] = src[(k0 + ty * 8 + i) * N + n0 + tx];
    __syncthreads();
    #pragma unroll
    for (int i = 0; i < 8; ++i)
      dst[(n0 + ty * 8 + i) * K + k0 + tx] = f2bf(ttile[tx][ty * 8 + i]);
    __syncthreads();
  }
}

// -------------------- fused attention + MLP (512 threads, 8 waves) --------
template<int K, int N>
__device__ __forceinline__ void mlp_layer(
    const unsigned short* __restrict__ xin, unsigned short* __restrict__ xout,
    const unsigned short* __restrict__ Wt, const float* __restrict__ bias,
    int lane, int wv, float* __restrict__ foutF)
{
  constexpr int NT = N / 128;      // tiles per wave (8 waves)
  const int ar  = lane & 15;
  const int akg = lane >> 4;
  f32x4 acc[NT];
  #pragma unroll
  for (int nt = 0; nt < NT; ++nt) acc[nt] = f32x4{0.f, 0.f, 0.f, 0.f};
  for (int ks = 0; ks < K / 32; ++ks) {
    const short8 a = *(const short8*)&xin[ar * 1032 + ks * 32 + akg * 8];
    #pragma unroll
    for (int nt = 0; nt < NT; ++nt) {
      const int n = wv * (N / 8) + nt * 16 + ar;
      const short8 b = *(const short8*)&Wt[n * K + ks * 32 + akg * 8];
      acc[nt] = __builtin_amdgcn_mfma_f32_16x16x32_bf16(a, b, acc[nt], 0, 0, 0);
    }
  }
  const int rbase = akg * 4;
  #pragma unroll
  for (int nt = 0; nt < NT; ++nt) {
    const int n = wv * (N / 8) + nt * 16 + ar;
    const float bv = bias[n];
    #pragma unroll
    for (int q = 0; q < 4; ++q) {
      float v = acc[nt][q] + bv;
      v = fmaxf(v, 0.f);
      xout[(rbase + q) * 1032 + n] = f2bf(v);
      if (foutF) foutF[(rbase + q) * 128 + n] = v;
    }
  }
}

__global__ __launch_bounds__(512) void attn_mlp_kernel(
    const float* __restrict__ fs, const float* __restrict__ fh, const float* __restrict__ fw,
    const float* __restrict__ Wa, const float* __restrict__ ba,
    const unsigned short* __restrict__ Wt,
    const float* __restrict__ b1, const float* __restrict__ b2,
    const float* __restrict__ b3, const float* __restrict__ b4,
    const float* __restrict__ Wo, const float* __restrict__ bo,
    float* __restrict__ out)
{
  __shared__ __align__(16) unsigned short xa[16 * 1032];
  __shared__ __align__(16) unsigned short xb[16 * 1032];
  __shared__ __align__(16) float sf_l[16 * 128];
  __shared__ __align__(16) float x4f[16 * 128];

  const int tid  = threadIdx.x;
  const int lane = tid & 63;
  const int wv   = tid >> 6;
  const int row0 = blockIdx.x * 16;

  // ---- attention over the 3 features (512 threads: 4 cols each) ----
  {
    const int i  = tid >> 5;            // 0..15
    const int j0 = (tid & 31) * 4;      // 0..124
    float wa[9], bav[3];
    #pragma unroll
    for (int q = 0; q < 9; ++q) wa[q] = Wa[q];
    #pragma unroll
    for (int q = 0; q < 3; ++q) bav[q] = ba[q];
    const int base = (row0 + i) * 128 + j0;
    const f32x4 a = *(const f32x4*)&fs[base];
    const f32x4 b = *(const f32x4*)&fh[base];
    const f32x4 c = *(const f32x4*)&fw[base];
    #pragma unroll
    for (int q = 0; q < 4; ++q) {
      const float f0 = a[q], f1 = b[q], f2 = c[q];
      float s0 = f0 * wa[0] + f1 * wa[3] + f2 * wa[6] + bav[0];
      float s1 = f0 * wa[1] + f1 * wa[4] + f2 * wa[7] + bav[1];
      float s2 = f0 * wa[2] + f1 * wa[5] + f2 * wa[8] + bav[2];
      s0 = fmaxf(s0, 0.f); s1 = fmaxf(s1, 0.f); s2 = fmaxf(s2, 0.f);
      const float m  = fmaxf(s0, fmaxf(s1, s2));
      const float e0 = __builtin_amdgcn_exp2f((s0 - m) * LOG2E);
      const float e1 = __builtin_amdgcn_exp2f((s1 - m) * LOG2E);
      const float e2 = __builtin_amdgcn_exp2f((s2 - m) * LOG2E);
      const float inv = __builtin_amdgcn_rcpf(e0 + e1 + e2);
      const float sf  = (f0 * e0 + f1 * e1 + f2 * e2) * inv;
      const int jj = j0 + q;
      sf_l[i * 128 + jj] = sf;
      xa[i * 1032 + jj]  = f2bf(sf);
    }
  }
  __syncthreads();

  mlp_layer<128, 1024>(xa, xb, Wt,          b1, lane, wv, nullptr);
  __syncthreads();
  mlp_layer<1024, 512>(xb, xa, Wt + 131072, b2, lane, wv, nullptr);
  __syncthreads();
  mlp_layer<512,  256>(xa, xb, Wt + 655360, b3, lane, wv, nullptr);
  __syncthreads();
  mlp_layer<256,  128>(xb, xa, Wt + 786432, b4, lane, wv, x4f);
  __syncthreads();

  // ---- residual + final Dense(1): 32 threads per row ----
  const int row = tid >> 5;
  const int p   = tid & 31;
  float part = 0.f;
  #pragma unroll
  for (int q = 0; q < 4; ++q) {
    const int jj = p + q * 32;
    part += (x4f[row * 128 + jj] + sf_l[row * 128 + jj]) * Wo[jj];
  }
  #pragma unroll
  for (int off = 16; off > 0; off >>= 1)
    part += __shfl_xor(part, off, 32);
  if (p == 0) out[row0 + row] = part + bo[0];
}

// -------------------- launch ----------------------------------------------
extern "C" void kernel_launch(void* const* d_in, const int* in_sizes, int n_in,
                              void* d_out, int out_size, void* d_ws, size_t ws_size,
                              hipStream_t stream) {
  const float* spatial  = (const float*)d_in[0];
  const int*   hour_idx = (const int*)d_in[1];
  const int*   week_idx = (const int*)d_in[2];
  const float* E_time   = (const float*)d_in[3];
  const float* E_week   = (const float*)d_in[4];
  const float* Ws_x = (const float*)d_in[5];
  const float* Ws_h = (const float*)d_in[6];
  const float* bs   = (const float*)d_in[7];
  const float* Wh_x = (const float*)d_in[8];
  const float* Wh_h = (const float*)d_in[9];
  const float* bh   = (const float*)d_in[10];
  const float* Ww_x = (const float*)d_in[11];
  const float* Ww_h = (const float*)d_in[12];
  const float* bw   = (const float*)d_in[13];
  const float* Wa   = (const float*)d_in[14];
  const float* ba   = (const float*)d_in[15];
  const float* W1   = (const float*)d_in[16];
  const float* b1   = (const float*)d_in[17];
  const float* W2   = (const float*)d_in[18];
  const float* b2   = (const float*)d_in[19];
  const float* W3   = (const float*)d_in[20];
  const float* b3   = (const float*)d_in[21];
  const float* W4   = (const float*)d_in[22];
  const float* b4   = (const float*)d_in[23];
  const float* Wo   = (const float*)d_in[24];
  const float* bo   = (const float*)d_in[25];
  float* out = (float*)d_out;

  float* ws    = (float*)d_ws;
  float* Ptime = ws;                     // 24*384
  float* Pweek = Ptime + 9216;           // 7*384
  float* fsb   = Pweek + 2688;           // 1024*128
  float* fhb   = fsb + 131072;
  float* fwb   = fhb + 131072;
  unsigned short* Wt = (unsigned short*)(fwb + 131072);  // 819200 bf16

  ptab_kernel<<<31, 256, 0, stream>>>(E_time, E_week, Wh_x, bh, Ww_x, bw, Ptime, Pweek);
  gru_kernel<<<192, 512, 0, stream>>>(spatial, hour_idx, week_idx, Ws_x,
      Ws_h, bs, Wh_h, bh, Ww_h, bw, Ptime, Pweek,
      W1, W2, W3, W4, Wt, fsb, fhb, fwb);
  attn_mlp_kernel<<<64, 512, 0, stream>>>(fsb, fhb, fwb, Wa, ba, Wt,
      b1, b2, b3, b4, Wo, bo, out);
}